// Round 4
// baseline (7994.559 us; speedup 1.0000x reference)
//
#include <hip/hip_runtime.h>
#include <hip/hip_bf16.h>

typedef __bf16 bf16;
typedef __bf16 bf16x8 __attribute__((ext_vector_type(8)));
typedef __bf16 bf16x4 __attribute__((ext_vector_type(4)));
typedef float floatx4 __attribute__((ext_vector_type(4)));

#define MFMA16(a, b, c) __builtin_amdgcn_mfma_f32_16x16x32_bf16((a), (b), (c), 0, 0, 0)

static constexpr int Bd = 64, Ld = 128, Ed = 512, Nd = 512, Hd = 1024;
static constexpr float LOG2E = 1.4426950408889634f;
static constexpr float TWO_LOG2E = 2.8853900817779268f;

__device__ __forceinline__ float fexp2(float x) { return __builtin_amdgcn_exp2f(x); }
__device__ __forceinline__ float frcp(float x) { return __builtin_amdgcn_rcpf(x); }
__device__ __forceinline__ float sigmoid_f(float x) { return frcp(1.0f + fexp2(-x * LOG2E)); }
__device__ __forceinline__ float tanh_f(float x) { return 1.0f - 2.0f * frcp(fexp2(x * TWO_LOG2E) + 1.0f); }

__device__ __forceinline__ bf16x8 cvt8(const float* p) {
    float4 f0 = *(const float4*)p;
    float4 f1 = *(const float4*)(p + 4);
    bf16x8 r = {(bf16)f0.x, (bf16)f0.y, (bf16)f0.z, (bf16)f0.w,
                (bf16)f1.x, (bf16)f1.y, (bf16)f1.z, (bf16)f1.w};
    return r;
}

// ---------------------------------------------------------------- f32 -> bf16 bulk convert (n % 8 == 0)
__global__ __launch_bounds__(256) void k_conv(const float* __restrict__ src, bf16* __restrict__ dst, int n) {
    int i0 = (blockIdx.x * 256 + threadIdx.x) * 8;
    if (i0 >= n) return;
    *(bf16x8*)(dst + i0) = cvt8(src + i0);
}

// ---------------------------------------------------------------- init: hb_bf16 = (bf16)state, hb_f32 = state
__global__ __launch_bounds__(256) void k_init(const float* __restrict__ state, bf16* __restrict__ hb,
                                              float* __restrict__ hb32) {
    int i0 = (blockIdx.x * 256 + threadIdx.x) * 8;   // 32 blocks -> 65536 el
    *(bf16x8*)(hb + i0) = cvt8(state + i0);
    *(float4*)(hb32 + i0) = *(const float4*)(state + i0);
    *(float4*)(hb32 + i0 + 4) = *(const float4*)(state + i0 + 4);
}

// ---------------------------------------------------------------- keys_c = (value @ Wk^T) * 2log2e  [bf16]
// GEMM M=B*N=32768, N=1024, K=1024. Block 256 thr = 4 waves, each wave 32x32.
__global__ __launch_bounds__(256) void k_keys(const bf16* __restrict__ val, const bf16* __restrict__ Wk,
                                              bf16* __restrict__ keys_c) {
    const int lane = threadIdx.x & 63, wave = threadIdx.x >> 6;
    const int l16 = lane & 15, q8 = (lane >> 4) * 8;
    const int mblk = blockIdx.x >> 4, nblk = blockIdx.x & 15;
    const int m_base = mblk * 64 + (wave & 1) * 32;
    const int n_base = nblk * 64 + (wave >> 1) * 32;
    const bf16* a0p = val + (size_t)(m_base + l16) * 1024 + q8;
    const bf16* a1p = a0p + 16 * 1024;
    const bf16* b0p = Wk + (size_t)(n_base + l16) * 1024 + q8;
    const bf16* b1p = b0p + 16 * 1024;
    floatx4 acc[2][2] = {};
    for (int k0 = 0; k0 < 1024; k0 += 32) {
        bf16x8 a0 = *(const bf16x8*)(a0p + k0);
        bf16x8 a1 = *(const bf16x8*)(a1p + k0);
        bf16x8 b0 = *(const bf16x8*)(b0p + k0);
        bf16x8 b1 = *(const bf16x8*)(b1p + k0);
        acc[0][0] = MFMA16(a0, b0, acc[0][0]);
        acc[0][1] = MFMA16(a0, b1, acc[0][1]);
        acc[1][0] = MFMA16(a1, b0, acc[1][0]);
        acc[1][1] = MFMA16(a1, b1, acc[1][1]);
    }
    const int mr = (lane >> 4) * 4;
    for (int im = 0; im < 2; im++)
        for (int in = 0; in < 2; in++)
            for (int r = 0; r < 4; r++) {
                int m = m_base + im * 16 + mr + r;
                int n = n_base + in * 16 + l16;
                keys_c[(size_t)m * 1024 + n] = (bf16)(acc[im][in][r] * TWO_LOG2E);
            }
}

// ---------------------------------------------------------------- per-step K1: GRU gates (emb f32, inline cvt)
// grid 256 x 64thr: block = (mt = b-tile of 16, js = j-slice of 16).
__global__ __launch_bounds__(64) void k_gru(const float* __restrict__ emb, const bf16* __restrict__ hb,
                                            const float* __restrict__ hb32,
                                            const bf16* __restrict__ Wih, const bf16* __restrict__ Whh,
                                            const float* __restrict__ bih, const float* __restrict__ bhh,
                                            bf16* __restrict__ rnn, float* __restrict__ context, int step) {
    const int lane = threadIdx.x;
    const int l16 = lane & 15, q8 = (lane >> 4) * 8;
    const int mt = blockIdx.x & 3, js = blockIdx.x >> 2;
    // zero the context accumulator for this step (consumed by k_attn_ctx atomics later)
    ((floatx4*)context)[blockIdx.x * 64 + lane] = (floatx4){0.f, 0.f, 0.f, 0.f};
    const int j_row = js * 16 + l16;
    const int b_row = mt * 16 + l16;
    floatx4 accR = {}, accZ = {}, accXN = {}, accHN = {};
    // segment 1: A = (bf16)emb[b_row*128+step, 0:512], B = Wih[:, 0:512]
    {
        const float* ae = emb + (size_t)(b_row * 128 + step) * 512 + q8;
        const bf16* w0 = Wih + (size_t)j_row * 1536 + q8;
        const bf16* w1 = Wih + (size_t)(1024 + j_row) * 1536 + q8;
        const bf16* w2 = Wih + (size_t)(2048 + j_row) * 1536 + q8;
        for (int k0 = 0; k0 < 512; k0 += 32) {
            bf16x8 a = cvt8(ae + k0);
            accR  = MFMA16(a, *(const bf16x8*)(w0 + k0), accR);
            accZ  = MFMA16(a, *(const bf16x8*)(w1 + k0), accZ);
            accXN = MFMA16(a, *(const bf16x8*)(w2 + k0), accXN);
        }
    }
    // segment 2: A = hb (bf16), B = Wih[:, 512:1536] and Whh
    {
        const bf16* ah = hb + (size_t)b_row * 1024 + q8;
        const bf16* u0 = Wih + (size_t)j_row * 1536 + 512 + q8;
        const bf16* u1 = Wih + (size_t)(1024 + j_row) * 1536 + 512 + q8;
        const bf16* u2 = Wih + (size_t)(2048 + j_row) * 1536 + 512 + q8;
        const bf16* v0 = Whh + (size_t)j_row * 1024 + q8;
        const bf16* v1 = Whh + (size_t)(1024 + j_row) * 1024 + q8;
        const bf16* v2 = Whh + (size_t)(2048 + j_row) * 1024 + q8;
        for (int k0 = 0; k0 < 1024; k0 += 32) {
            bf16x8 a = *(const bf16x8*)(ah + k0);
            accR  = MFMA16(a, *(const bf16x8*)(u0 + k0), accR);
            accZ  = MFMA16(a, *(const bf16x8*)(u1 + k0), accZ);
            accXN = MFMA16(a, *(const bf16x8*)(u2 + k0), accXN);
            accHN = MFMA16(a, *(const bf16x8*)(v2 + k0), accHN);
            accR  = MFMA16(a, *(const bf16x8*)(v0 + k0), accR);
            accZ  = MFMA16(a, *(const bf16x8*)(v1 + k0), accZ);
        }
    }
    const int mr = (lane >> 4) * 4;
    const int j = js * 16 + l16;
    const float br  = bih[j] + bhh[j];
    const float bz  = bih[1024 + j] + bhh[1024 + j];
    const float bxn = bih[2048 + j];
    const float bhn = bhh[2048 + j];
    for (int r = 0; r < 4; r++) {
        int b = mt * 16 + mr + r;
        float rg = sigmoid_f(accR[r] + br);
        float zg = sigmoid_f(accZ[r] + bz);
        float ng = tanh_f(accXN[r] + bxn + rg * (accHN[r] + bhn));
        float hp = hb32[(size_t)b * 1024 + j];
        rnn[(size_t)b * 1024 + j] = (bf16)((1.0f - zg) * ng + zg * hp);
    }
}

// ---------------------------------------------------------------- per-step K2: qc = (rnn @ Wq^T) * 2log2e [fp32]
__global__ __launch_bounds__(64) void k_q(const bf16* __restrict__ rnn, const bf16* __restrict__ Wq,
                                          float* __restrict__ qc) {
    const int lane = threadIdx.x;
    const int l16 = lane & 15, q8 = (lane >> 4) * 8;
    const int mt = blockIdx.x & 3, is = blockIdx.x >> 2;
    const bf16* ap = rnn + (size_t)(mt * 16 + l16) * 1024 + q8;
    const bf16* bp = Wq + (size_t)(is * 16 + l16) * 1024 + q8;
    floatx4 acc = {};
    for (int k0 = 0; k0 < 1024; k0 += 32)
        acc = MFMA16(*(const bf16x8*)(ap + k0), *(const bf16x8*)(bp + k0), acc);
    const int mr = (lane >> 4) * 4;
    for (int r = 0; r < 4; r++) {
        int b = mt * 16 + mr + r;
        int i = is * 16 + l16;
        qc[(size_t)b * 1024 + i] = acc[r] * TWO_LOG2E;
    }
}

// ---------------------------------------------------------------- per-step K3: scores[b,n] = sum_h v*tanh(q+k)
// tanh via 1 - 2*rcp(exp2(qc+kc)+1); qc/kc pre-scaled by 2log2e. Block = (b, 4 n), wave per n.
__global__ __launch_bounds__(256) void k_score(const bf16* __restrict__ keys_c, const float* __restrict__ qc,
                                               const float* __restrict__ v_att, float* __restrict__ scores) {
    const int b = blockIdx.x >> 7, nq = blockIdx.x & 127;
    const int wave = threadIdx.x >> 6, lane = threadIdx.x & 63;
    const int n = nq * 4 + wave;
    const bf16* kp = keys_c + (size_t)(b * 512 + n) * 1024;
    const float* qp = qc + (size_t)b * 1024;
    float acc = 0.0f;
#pragma unroll
    for (int c = 0; c < 2; c++) {
        const int h0 = c * 512 + lane * 8;
        bf16x8 kv = *(const bf16x8*)(kp + h0);
        float4 va = *(const float4*)(v_att + h0);
        float4 vb = *(const float4*)(v_att + h0 + 4);
        float vv[8] = {va.x, va.y, va.z, va.w, vb.x, vb.y, vb.z, vb.w};
        float4 qa = *(const float4*)(qp + h0);
        float4 qb = *(const float4*)(qp + h0 + 4);
        float qv[8] = {qa.x, qa.y, qa.z, qa.w, qb.x, qb.y, qb.z, qb.w};
#pragma unroll
        for (int jj = 0; jj < 8; jj++) {
            float x = qv[jj] + (float)kv[jj];
            float t = fexp2(x);
            float rr = frcp(t + 1.0f);
            float tv = __builtin_fmaf(-2.0f, rr, 1.0f);
            acc = __builtin_fmaf(vv[jj], tv, acc);
        }
    }
#pragma unroll
    for (int off = 32; off > 0; off >>= 1) acc += __shfl_down(acc, off, 64);
    if (lane == 0) scores[(size_t)b * 512 + n] = acc;
}

// ---------------------------------------------------------------- per-step K4: softmax (redundant per chunk) + context partial
// grid 256 (= b*4 chunks) x 256 thr. Writes attns output f32 (chunk 0), atomically accumulates context fp32.
__global__ __launch_bounds__(256) void k_attn_ctx(const float* __restrict__ scores, const float* __restrict__ mask,
                                                  const bf16* __restrict__ value, float* __restrict__ context,
                                                  float* __restrict__ out_base, int step) {
    const int b = blockIdx.x >> 2, chunk = blockIdx.x & 3;
    const int t = threadIdx.x;
    __shared__ float sm[512];
    __shared__ float red[256];
    float s0 = scores[(size_t)b * 512 + t];
    float s1 = scores[(size_t)b * 512 + 256 + t];
    if (!(mask[(size_t)b * 512 + t] > 0.f)) s0 = -1e9f;
    if (!(mask[(size_t)b * 512 + 256 + t] > 0.f)) s1 = -1e9f;
    red[t] = fmaxf(s0, s1);
    __syncthreads();
    for (int s = 128; s > 0; s >>= 1) {
        if (t < s) red[t] = fmaxf(red[t], red[t + s]);
        __syncthreads();
    }
    float mx = red[0];
    __syncthreads();
    float p0 = fexp2((s0 - mx) * LOG2E);
    float p1 = fexp2((s1 - mx) * LOG2E);
    red[t] = p0 + p1;
    __syncthreads();
    for (int s = 128; s > 0; s >>= 1) {
        if (t < s) red[t] += red[t + s];
        __syncthreads();
    }
    float inv = frcp(red[0]);
    sm[t] = p0 * inv;
    sm[256 + t] = p1 * inv;
    __syncthreads();
    if (chunk == 0) {
        float* ao = out_base + (size_t)Bd * Ld * Hd + (size_t)(b * 128 + step) * 512;
        ao[t] = sm[t];
        ao[256 + t] = sm[256 + t];
    }
    const int h0 = t * 4;
    float c0 = 0.f, c1 = 0.f, c2 = 0.f, c3 = 0.f;
    const bf16* vb = value + (size_t)b * 512 * 1024 + h0;
    for (int n = chunk * 128; n < chunk * 128 + 128; n++) {
        float a = sm[n];
        bf16x4 vv = *(const bf16x4*)(vb + (size_t)n * 1024);
        c0 = __builtin_fmaf(a, (float)vv[0], c0);
        c1 = __builtin_fmaf(a, (float)vv[1], c1);
        c2 = __builtin_fmaf(a, (float)vv[2], c2);
        c3 = __builtin_fmaf(a, (float)vv[3], c3);
    }
    float* cp = context + (size_t)b * 1024 + h0;
    atomicAdd(cp + 0, c0);
    atomicAdd(cp + 1, c1);
    atomicAdd(cp + 2, c2);
    atomicAdd(cp + 3, c3);
}

// ---------------------------------------------------------------- per-step K5: new_state = tanh([rnn|ctx] @ Wm^T + bm)
__global__ __launch_bounds__(64) void k_out(const bf16* __restrict__ rnn, const float* __restrict__ context,
                                            const bf16* __restrict__ Wm, const float* __restrict__ bm,
                                            float* __restrict__ out, bf16* __restrict__ hb,
                                            float* __restrict__ hb32, int step) {
    const int lane = threadIdx.x;
    const int l16 = lane & 15, q8 = (lane >> 4) * 8;
    const int mt = blockIdx.x & 3, is = blockIdx.x >> 2;
    const int b_row = mt * 16 + l16;
    const bf16* ar = rnn + (size_t)b_row * 1024 + q8;
    const float* ac = context + (size_t)b_row * 1024 + q8;
    const bf16* bp = Wm + (size_t)(is * 16 + l16) * 2048 + q8;
    floatx4 acc = {};
    for (int k0 = 0; k0 < 1024; k0 += 32) {
        bf16x8 a = *(const bf16x8*)(ar + k0);
        acc = MFMA16(a, *(const bf16x8*)(bp + k0), acc);
    }
    for (int k0 = 0; k0 < 1024; k0 += 32) {
        bf16x8 a = cvt8(ac + k0);
        acc = MFMA16(a, *(const bf16x8*)(bp + 1024 + k0), acc);
    }
    const int mr = (lane >> 4) * 4;
    for (int r = 0; r < 4; r++) {
        int b = mt * 16 + mr + r;
        int i = is * 16 + l16;
        float h = tanh_f(acc[r] + bm[i]);
        out[(size_t)(b * 128 + step) * 1024 + i] = h;
        hb[(size_t)b * 1024 + i] = (bf16)h;
        hb32[(size_t)b * 1024 + i] = h;
    }
}

extern "C" void kernel_launch(void* const* d_in, const int* in_sizes, int n_in,
                              void* d_out, int out_size, void* d_ws, size_t ws_size,
                              hipStream_t stream) {
    const float* emb   = (const float*)d_in[0];
    const float* value = (const float*)d_in[1];
    const float* mask  = (const float*)d_in[2];
    const float* state = (const float*)d_in[3];
    const float* Wih   = (const float*)d_in[4];
    const float* bih   = (const float*)d_in[5];
    const float* Whh   = (const float*)d_in[6];
    const float* bhh   = (const float*)d_in[7];
    const float* Wq    = (const float*)d_in[8];
    const float* Wk    = (const float*)d_in[9];
    const float* v_att = (const float*)d_in[10];
    const float* Wm    = (const float*)d_in[11];
    const float* bm    = (const float*)d_in[12];

    // ws layout (bytes); total = 159,514,624 (< 167.7 MB confirmed available)
    char* ws = (char*)d_ws;
    bf16*  hb      = (bf16*)(ws);                  //     131,072
    float* hb32    = (float*)(ws + 131072);        //     262,144
    bf16*  rnn     = (bf16*)(ws + 393216);         //     131,072
    float* qc      = (float*)(ws + 524288);        //     262,144
    float* scores  = (float*)(ws + 786432);        //     131,072
    float* context = (float*)(ws + 917504);        //     262,144
    bf16*  value_c = (bf16*)(ws + 1179648);        //  67,108,864
    bf16*  Wih_c   = (bf16*)(ws + 68288512);       //   9,437,184
    bf16*  Whh_c   = (bf16*)(ws + 77725696);       //   6,291,456
    bf16*  Wq_c    = (bf16*)(ws + 84017152);       //   2,097,152
    bf16*  Wk_c    = (bf16*)(ws + 86114304);       //   2,097,152
    bf16*  Wm_c    = (bf16*)(ws + 88211456);       //   4,194,304
    bf16*  keys_c  = (bf16*)(ws + 92405760);       //  67,108,864

    float* out_f = (float*)d_out;   // [B*L*H outputs | B*L*N attns], f32

    // one-time conversions (f32 -> bf16) for MFMA operands
    k_conv<<<16384, 256, 0, stream>>>(value, value_c, 33554432);
    k_conv<<<2304,  256, 0, stream>>>(Wih,   Wih_c,   4718592);
    k_conv<<<1536,  256, 0, stream>>>(Whh,   Whh_c,   3145728);
    k_conv<<<512,   256, 0, stream>>>(Wq,    Wq_c,    1048576);
    k_conv<<<512,   256, 0, stream>>>(Wk,    Wk_c,    1048576);
    k_conv<<<1024,  256, 0, stream>>>(Wm,    Wm_c,    2097152);
    k_init<<<32,    256, 0, stream>>>(state, hb, hb32);

    k_keys<<<8192, 256, 0, stream>>>(value_c, Wk_c, keys_c);

    for (int step = 0; step < Ld; step++) {
        k_gru<<<256, 64, 0, stream>>>(emb, hb, hb32, Wih_c, Whh_c, bih, bhh, rnn, context, step);
        k_q<<<256, 64, 0, stream>>>(rnn, Wq_c, qc);
        k_score<<<8192, 256, 0, stream>>>(keys_c, qc, v_att, scores);
        k_attn_ctx<<<256, 256, 0, stream>>>(scores, mask, value_c, context, out_f, step);
        k_out<<<256, 64, 0, stream>>>(rnn, context, Wm_c, bm, out_f, hb, hb32, step);
    }
}